// Round 8
// baseline (143.233 us; speedup 1.0000x reference)
//
#include <hip/hip_runtime.h>
#include <cstddef>

namespace {
constexpr int B = 4, C = 64, H = 256, W = 256;
constexpr int HW = H * W;      // 65536
constexpr int CHW = C * HW;    // 4194304
constexpr int CG = 4;          // channel groups for edge
constexpr int TH = 16;         // strip height for fused blur (22 KB LDS -> 7 blocks/CU)
constexpr float SMIN = 0.6f, SMAX = 1.2f;
}

__device__ __forceinline__ float4 ld4(const float* p) {
  return *(const float4*)p;
}
__device__ __forceinline__ void st4(float* p, float a, float b, float c, float d) {
  float4 v; v.x = a; v.y = b; v.z = c; v.w = d; *(float4*)p = v;
}

// Block per (b, cg, 4-row band), XCD-band swizzled: xcd = blockIdx%8 owns rows
// [xcd*32, xcd*32+32), bands iterate fastest within (cg,b) so halo rows of
// adjacent bands stream through the same XCD's L2. Each wave handles 4
// channels fully unrolled; per channel it loads 6 rows (rolling halo) and
// emits 4 rows of Sobel-energy partials -> 1.5x logical reads instead of 3x.
// lane l owns columns 4l..4l+3 (wave == row); horizontal neighbors via shfl.
// Partial sums (16 channels) -> P[cg][b][h][w]. Block 0 also inits mm.
__global__ __launch_bounds__(256) void edge_kernel(
    const float* __restrict__ x, float* __restrict__ P,
    unsigned int* __restrict__ mm) {
  __shared__ float part[4][4][64][4];   // [wave][row][lane][px]
  if (blockIdx.x == 0 && threadIdx.x < 2 * B)
    mm[threadIdx.x] = (threadIdx.x < B) ? 0x7f7fffffu : 0u;
  const int xcd = blockIdx.x & 7;
  const int slot = blockIdx.x >> 3;          // 0..127
  const int hbb = slot & 7;                  // band within the XCD's 32 rows
  const int cb = slot >> 3;                  // 0..15 = cg*B + b
  const int h0 = xcd * 32 + hbb * 4;
  const int cg = cb >> 2;
  const int b = cb & 3;
  const int lane = threadIdx.x & 63, wv = threadIdx.x >> 6;
  const float* base = x + (size_t)b * CHW + 4 * lane;
  const int c0 = cg * 16 + wv * 4;
  float acc[4][4] = {};
  #pragma unroll
  for (int cc = 0; cc < 4; ++cc) {
    const float* p = base + (size_t)(c0 + cc) * HW;
    float4 R[6];
    #pragma unroll
    for (int i = 0; i < 6; ++i) {
      const int gh = h0 - 1 + i;
      R[i] = (gh >= 0 && gh < H) ? ld4(p + (size_t)gh * W)
                                 : float4{0.f, 0.f, 0.f, 0.f};
    }
    float Lh[6], Rh[6];
    #pragma unroll
    for (int i = 0; i < 6; ++i) {
      Lh[i] = __shfl_up(R[i].w, 1);
      Rh[i] = __shfl_down(R[i].x, 1);
    }
    if (lane == 0) {
      #pragma unroll
      for (int i = 0; i < 6; ++i) Lh[i] = 0.f;
    }
    if (lane == 63) {
      #pragma unroll
      for (int i = 0; i < 6; ++i) Rh[i] = 0.f;
    }
    #pragma unroll
    for (int r = 0; r < 4; ++r) {
      const float ra[6] = {Lh[r],     R[r].x,     R[r].y,     R[r].z,     R[r].w,     Rh[r]};
      const float rb[6] = {Lh[r + 1], R[r + 1].x, R[r + 1].y, R[r + 1].z, R[r + 1].w, Rh[r + 1]};
      const float rc[6] = {Lh[r + 2], R[r + 2].x, R[r + 2].y, R[r + 2].z, R[r + 2].w, Rh[r + 2]};
      #pragma unroll
      for (int j = 0; j < 4; ++j) {
        float gx = (ra[j + 2] - ra[j]) + 2.f * (rb[j + 2] - rb[j]) + (rc[j + 2] - rc[j]);
        float gy = (rc[j] - ra[j]) + 2.f * (rc[j + 1] - ra[j + 1]) + (rc[j + 2] - ra[j + 2]);
        acc[r][j] = fmaf(gx, gx, acc[r][j]);
        acc[r][j] = fmaf(gy, gy, acc[r][j]);
      }
    }
  }
  #pragma unroll
  for (int r = 0; r < 4; ++r)
    #pragma unroll
    for (int j = 0; j < 4; ++j) part[wv][r][lane][j] = acc[r][j];
  __syncthreads();
  {
    const int r = wv;                       // wave wv combines + writes row wv
    float s[4];
    #pragma unroll
    for (int j = 0; j < 4; ++j)
      s[j] = part[0][r][lane][j] + part[1][r][lane][j] +
             part[2][r][lane][j] + part[3][r][lane][j];
    st4(P + (size_t)(cg * B + b) * HW + (size_t)(h0 + r) * W + 4 * lane,
        s[0], s[1], s[2], s[3]);
  }
}

// Sum the 4 partial planes -> edge; per-batch min/max reduce -> mm atomics.
__global__ __launch_bounds__(256) void combine_kernel(
    const float* __restrict__ P, float* __restrict__ edge,
    unsigned int* __restrict__ mm) {
  __shared__ float smn[4], smx[4];
  const int t = blockIdx.x * 256 + threadIdx.x;
  const int pix4 = t * 4;
  const int b = pix4 >> 16;
  const int off = pix4 & (HW - 1);
  float4 s0 = ld4(P + (size_t)(0 * B + b) * HW + off);
  float4 s1 = ld4(P + (size_t)(1 * B + b) * HW + off);
  float4 s2 = ld4(P + (size_t)(2 * B + b) * HW + off);
  float4 s3 = ld4(P + (size_t)(3 * B + b) * HW + off);
  float e0 = (s0.x + s1.x + s2.x + s3.x) * (1.f / 64.f);
  float e1 = (s0.y + s1.y + s2.y + s3.y) * (1.f / 64.f);
  float e2 = (s0.z + s1.z + s2.z + s3.z) * (1.f / 64.f);
  float e3 = (s0.w + s1.w + s2.w + s3.w) * (1.f / 64.f);
  st4(edge + pix4, e0, e1, e2, e3);
  float mn = fminf(fminf(e0, e1), fminf(e2, e3));
  float mx = fmaxf(fmaxf(e0, e1), fmaxf(e2, e3));
  #pragma unroll
  for (int o = 32; o > 0; o >>= 1) {
    mn = fminf(mn, __shfl_down(mn, o, 64));
    mx = fmaxf(mx, __shfl_down(mx, o, 64));
  }
  const int lane = threadIdx.x & 63, wv = threadIdx.x >> 6;
  if (lane == 0) { smn[wv] = mn; smx[wv] = mx; }
  __syncthreads();
  if (threadIdx.x == 0) {
    mn = fminf(fminf(smn[0], smn[1]), fminf(smn[2], smn[3]));
    mx = fmaxf(fmaxf(smx[0], smx[1]), fmaxf(smx[2], smx[3]));
    atomicMin(mm + b, __float_as_uint(mn));       // edge >= 0: float order == uint order
    atomicMax(mm + B + b, __float_as_uint(mx));
  }
}

// Per-pixel weight table: wt[b][h][w] = {e1, inv}. Full 7-tap kernel is
// reconstructed with 4 muls: taps {e9,e4,e1,1,e1,e4,e9}*inv.
__global__ __launch_bounds__(256) void weights_kernel(
    const float* __restrict__ edge, const unsigned int* __restrict__ mm,
    float* __restrict__ wt) {
  const int t = blockIdx.x * 256 + threadIdx.x;
  const int pix4 = t * 4;
  const int b = pix4 >> 16;
  const float emin = __uint_as_float(mm[b]);
  const float inv_den = 1.f / (__uint_as_float(mm[B + b]) + 1e-6f);
  float4 ev = ld4(edge + pix4);
  const float E[4] = {ev.x, ev.y, ev.z, ev.w};
  float r[8];
  #pragma unroll
  for (int j = 0; j < 4; ++j) {
    float en = (E[j] - emin) * inv_den;
    float sg = SMIN + (SMAX - SMIN) * en;
    float a = 1.0f / (2.0f * sg * sg);
    float e1 = __expf(-a);
    float t2 = e1 * e1, e4 = t2 * t2, e9 = e4 * e4 * e1;
    float inv = 1.f / (1.f + 2.f * (e1 + e4 + e9));
    r[2 * j] = e1; r[2 * j + 1] = inv;
  }
  st4(wt + (size_t)pix4 * 2,     r[0], r[1], r[2], r[3]);
  st4(wt + (size_t)pix4 * 2 + 4, r[4], r[5], r[6], r[7]);
}

__device__ __forceinline__ void recon_g(float e1, float inv, float g[7]) {
  float t2 = e1 * e1, e4 = t2 * t2, e9 = e4 * e4 * e1;
  g[3] = inv; g[2] = e1 * inv; g[1] = e4 * inv; g[0] = e9 * inv;
  g[4] = g[2]; g[5] = g[1]; g[6] = g[0];
}

// Fused h+v blur. Block per (b, c, 16-row strip): stage TH+6 hblurred rows in
// LDS (22 KB -> 7 blocks/CU, 87% occupancy), one barrier, vblur with rolling
// 7-row register window, store to out. XCD swizzle keeps strips of the same
// plane on one XCD so halo rows hit the local L2.
// TH=64 (R6): 70 KB LDS, 2 blocks/CU -> latency-bound regression (47 us).
// TH=32 (R7): 4 blocks/CU, under the 40 us fill floor. TH=16: max occupancy.
__global__ __launch_bounds__(256) void fusedblur_kernel(
    const float* __restrict__ x, const float* __restrict__ wt,
    float* __restrict__ out) {
  __shared__ float hb[TH + 6][W];
  const int xcd = blockIdx.x & 7;
  const int slot = blockIdx.x >> 3;              // 0..511
  const int s = slot & 15;                       // strip (H/TH == 16)
  const int bc = xcd * 32 + (slot >> 4);         // b*C + c
  const int b = bc >> 6;
  const int h0 = s * TH;
  const int lane = threadIdx.x & 63, wv = threadIdx.x >> 6;
  const float* xp = x + (size_t)bc * HW + 4 * lane;
  const float* wp = wt + (size_t)b * HW * 2 + 8 * lane;
  float* op = out + (size_t)bc * HW + 4 * lane;

  // Stage 1: hblur rows h0-3 .. h0+TH+2 into LDS (zero rows outside image).
  for (int r = wv; r < TH + 6; r += 4) {
    const int gh = h0 - 3 + r;
    float4 o = {0.f, 0.f, 0.f, 0.f};
    if (gh >= 0 && gh < H) {
      float4 v = ld4(xp + (size_t)gh * W);
      float4 q0 = ld4(wp + (size_t)gh * W * 2);
      float4 q1 = ld4(wp + (size_t)gh * W * 2 + 4);
      float L1 = __shfl_up(v.y, 1), L2 = __shfl_up(v.z, 1), L3 = __shfl_up(v.w, 1);
      float R1 = __shfl_down(v.x, 1), R2 = __shfl_down(v.y, 1), R3 = __shfl_down(v.z, 1);
      if (lane == 0)  { L1 = 0.f; L2 = 0.f; L3 = 0.f; }
      if (lane == 63) { R1 = 0.f; R2 = 0.f; R3 = 0.f; }
      const float win[10] = {L1, L2, L3, v.x, v.y, v.z, v.w, R1, R2, R3};
      const float E1[4] = {q0.x, q0.z, q1.x, q1.z};
      const float IV[4] = {q0.y, q0.w, q1.y, q1.w};
      float acc[4];
      #pragma unroll
      for (int j = 0; j < 4; ++j) {
        float g[7]; recon_g(E1[j], IV[j], g);
        float sacc = g[0] * win[j];
        #pragma unroll
        for (int i = 1; i < 7; ++i) sacc = fmaf(g[i], win[j + i], sacc);
        acc[j] = sacc;
      }
      o.x = acc[0]; o.y = acc[1]; o.z = acc[2]; o.w = acc[3];
    }
    *(float4*)&hb[r][4 * lane] = o;
  }
  __syncthreads();

  // Stage 2: vblur. Wave wv owns output rows [wv*4, wv*4+4), rolling window.
  const int r0 = wv * 4;
  float win7[7][4];
  #pragma unroll
  for (int i = 0; i < 7; ++i) {
    float4 v = *(const float4*)&hb[r0 + i][4 * lane];
    win7[i][0] = v.x; win7[i][1] = v.y; win7[i][2] = v.z; win7[i][3] = v.w;
  }
  #pragma unroll
  for (int k = 0; k < 4; ++k) {
    const int gh = h0 + r0 + k;
    float4 q0 = ld4(wp + (size_t)gh * W * 2);
    float4 q1 = ld4(wp + (size_t)gh * W * 2 + 4);
    const float E1[4] = {q0.x, q0.z, q1.x, q1.z};
    const float IV[4] = {q0.y, q0.w, q1.y, q1.w};
    float acc[4];
    #pragma unroll
    for (int j = 0; j < 4; ++j) {
      float g[7]; recon_g(E1[j], IV[j], g);
      float sacc = g[0] * win7[0][j];
      #pragma unroll
      for (int i = 1; i < 7; ++i) sacc = fmaf(g[i], win7[i][j], sacc);
      acc[j] = sacc;
    }
    st4(op + (size_t)gh * W, acc[0], acc[1], acc[2], acc[3]);
    if (k < 3) {
      #pragma unroll
      for (int i = 0; i < 6; ++i) {
        #pragma unroll
        for (int j = 0; j < 4; ++j) win7[i][j] = win7[i + 1][j];
      }
      float4 nv = *(const float4*)&hb[r0 + k + 7][4 * lane];
      win7[6][0] = nv.x; win7[6][1] = nv.y; win7[6][2] = nv.z; win7[6][3] = nv.w;
    }
  }
}

extern "C" void kernel_launch(void* const* d_in, const int* in_sizes, int n_in,
                              void* d_out, int out_size, void* d_ws, size_t ws_size,
                              hipStream_t stream) {
  const float* x = (const float*)d_in[0];
  float* out = (float*)d_out;

  unsigned int* mm = (unsigned int*)d_ws;                        // 2*B uints
  float* edge = (float*)((char*)d_ws + 1024);                    // B*HW floats (1 MB)
  float* wt = (float*)((char*)d_ws + 1024 + (size_t)B * HW * 4); // B*HW*2 floats (2 MB)

  // Edge partial planes live in d_out (CG*B*HW floats = 4 MB); overwritten
  // later by the fused blur, which writes every output element.
  float* P = out;

  edge_kernel<<<B * CG * (H / 4), 256, 0, stream>>>(x, P, mm);
  combine_kernel<<<(B * HW / 4) / 256, 256, 0, stream>>>(P, edge, mm);
  weights_kernel<<<(B * HW / 4) / 256, 256, 0, stream>>>(edge, mm, wt);
  fusedblur_kernel<<<B * C * (H / TH), 256, 0, stream>>>(x, wt, out);
}